// Round 3
// baseline (262.098 us; speedup 1.0000x reference)
//
#include <hip/hip_runtime.h>
#include <cstdint>
#include <cstddef>

#define NROWS 8192
#define DIM   25
#define CIN   128
#define COUT  128
#define MAXT  160

// ---------------- compile-time path tables (mirrors reference _build_paths) --
struct Tables {
  int   w_idx[MAXT];     // per original entry t: weight row
  float coef[MAXT];      // per original entry t: signed coefficient
  int   o_start[DIM + 1];
  int   e_in[MAXT];      // bucketed-by-o: input DIM row
  int   e_t[MAXT];       // bucketed-by-o: original entry index (row of Bt)
  int   T;
};

constexpr Tables build_tables() {
  Tables tb{};
  int off[5] = {0, 1, 4, 9, 16};
  const float pn = 0.44721359549995793f;  // 1/sqrt(5)
  int in_idx[MAXT] = {}, out_idx[MAXT] = {}, widx[MAXT] = {};
  float cf[MAXT] = {};
  int T = 0, w = 0;
  for (int lo = 0; lo < 5; ++lo) {
    for (int li = 0; li < 5; ++li) {
      int oi = off[li], oo = off[lo];
      in_idx[T] = oi + li; out_idx[T] = oo + lo; widx[T] = w; cf[T] = pn; ++T; ++w;
      int mm = li < lo ? li : lo;
      for (int m = 1; m <= mm; ++m) {
        int ip = oi + li + m, im = oi + li - m;
        int op = oo + lo + m, om = oo + lo - m;
        int wre = w, wim = w + 1; w += 2;
        in_idx[T] = ip; out_idx[T] = op; widx[T] = wre; cf[T] = pn;  ++T;
        in_idx[T] = im; out_idx[T] = om; widx[T] = wre; cf[T] = pn;  ++T;
        in_idx[T] = ip; out_idx[T] = om; widx[T] = wim; cf[T] = pn;  ++T;
        in_idx[T] = im; out_idx[T] = op; widx[T] = wim; cf[T] = -pn; ++T;
      }
    }
  }
  tb.T = T;  // 145
  for (int t = 0; t < T; ++t) { tb.w_idx[t] = widx[t]; tb.coef[t] = cf[t]; }
  int pos = 0;
  for (int o = 0; o < DIM; ++o) {
    tb.o_start[o] = pos;
    for (int t = 0; t < T; ++t)
      if (out_idx[t] == o) { tb.e_in[pos] = in_idx[t]; tb.e_t[pos] = t; ++pos; }
  }
  tb.o_start[DIM] = pos;
  return tb;
}

__constant__ Tables TAB = build_tables();

// ---------------- helpers ----------------------------------------------------
__device__ __forceinline__ uint16_t f2bf(float f) {
  uint32_t u = __float_as_uint(f);
  uint32_t r = (u + 0x7FFFu + ((u >> 16) & 1u)) >> 16;
  return (uint16_t)r;
}

__device__ __forceinline__ void load_lds16(const void* g, void* l) {
  __builtin_amdgcn_global_load_lds(
      (const __attribute__((address_space(1))) uint32_t*)g,
      (__attribute__((address_space(3))) uint32_t*)l, 16, 0, 0);
}

typedef __bf16 v8bf __attribute__((ext_vector_type(8)));
typedef float  v4f  __attribute__((ext_vector_type(4)));

// pack two float4 into 8 bf16 (compiler emits v_cvt_pk_bf16_f32 — RNE)
__device__ __forceinline__ v8bf cvt8(float4 p, float4 q) {
  v8bf v;
  v[0] = (__bf16)p.x; v[1] = (__bf16)p.y; v[2] = (__bf16)p.z; v[3] = (__bf16)p.w;
  v[4] = (__bf16)q.x; v[5] = (__bf16)q.y; v[6] = (__bf16)q.z; v[7] = (__bf16)q.w;
  return v;
}

// ---------------- kernel 1: weight prep only ---------------------------------
// LDS-tiled transpose+scale of weights: Bt[t][d][c] = coef[t]*W[w_idx[t]][c][d]
// 4 blocks per t (32 d each). ~2 MB of traffic -> a few microseconds.
#define NWB  (145 * 4)

__global__ void prep_kernel(const float* __restrict__ W, uint16_t* __restrict__ Bt) {
  __shared__ float tile[128][33];
  int b  = blockIdx.x;
  int t  = b >> 2;
  int d0 = (b & 3) << 5;                  // 32 d-values per block
  int w  = TAB.w_idx[t];
  float cf = TAB.coef[t];
  const float* Wp = W + (size_t)w * CIN * COUT;
  uint16_t* Bp = Bt + (size_t)t * CIN * COUT;
  int tid = threadIdx.x;
  // read: coalesced 32-float (128B) rows of W[c][d0..d0+31]
  {
    int dcol = tid & 31, cbase = tid >> 5;     // 8 c-rows per pass
    #pragma unroll
    for (int r = 0; r < 16; ++r) {
      int c = (r << 3) + cbase;
      tile[c][dcol] = cf * Wp[(size_t)c * COUT + d0 + dcol];
    }
  }
  __syncthreads();
  // write: coalesced bf16 rows of Bt[t][d][c] (c contiguous)
  {
    int c = tid & 127, dbase = tid >> 7;       // 2 d-rows per pass
    #pragma unroll
    for (int r = 0; r < 16; ++r) {
      int dd = (r << 1) + dbase;
      Bp[(size_t)(d0 + dd) * CIN + c] = f2bf(tile[c][dd]);
    }
  }
}

// ---------------- kernel 2: fused cast + grouped GEMM ------------------------
// Per block: Out[n0..n0+255][o][0..127] = sum_e X[n][IN[e]][:] . Bt[e_t][:][:]
// Round-3: A is read DIRECTLY from fp32 X (no Xb materialization pass):
//   T14 async-STAGE split — per K-step each thread issues 8 global dwordx4 of
//   X BEFORE the MFMA phase (latency hides under compute; the barrier's
//   vmcnt(0) drain lands a full compute phase after issue), then after the
//   post-compute barrier converts to bf16 (native casts -> v_cvt_pk_bf16_f32)
//   and ds_write_b128s into the XOR-swizzled As layout. Registers are the
//   second buffer, so As stays single-buffered.
// B keeps global_load_lds, now double-buffered so its issue overlaps compute.
// LDS = As 32K + Bs 2x16K = 64 KB; VGPR-capped 2 blocks/CU (16 waves) either
// way, so the extra LDS is free. __launch_bounds__(512,4) pins VGPR <= 128.
// Grid: XCD-aware, o sweeps fastest so each 3.2 MB X slab is L2-reused 25x.
__global__ __launch_bounds__(512, 4) void so2_gemm(
    const float* __restrict__ X,       // [NROWS][DIM][CIN] fp32
    const uint16_t* __restrict__ Bt,   // [T][COUT][CIN]    bf16 bits
    float* __restrict__ Out) {         // [NROWS][DIM][COUT]
  __shared__ __align__(16) uint16_t As[256 * 64];      // 32 KB, single buffer
  __shared__ __align__(16) uint16_t Bs[2][128 * 64];   // 2 x 16 KB

  // XCD-aware decode: lb -> (o, n-tile)
  const int lb   = blockIdx.x;            // 0..799
  const int xcd  = lb & 7;
  const int slot = lb >> 3;               // 0..99
  const int o    = slot % 25;             // o sweeps fastest within an XCD
  const int nt   = xcd + ((slot / 25) << 3);   // 0..31
  const int n0   = nt << 8;               // 256 rows per tile

  const int e0 = TAB.o_start[o];
  const int nE = TAB.o_start[o + 1] - e0;

  const int tid  = threadIdx.x;
  const int w    = tid >> 6;              // 0..7
  const int l    = tid & 63;

  // B staging (global_load_lds, proven r2 geometry):
  // dest byte = w*1024 + l*16 (+ issue offset) = wave-uniform base + lane*16
  const int srow = (w << 3) + (l >> 3);          // 0..63
  const int slt  = l & 7;
  const int ssrc = ((slt ^ (l >> 3)) << 3);      // pre-swizzled global chunk

  // A staging (reg + ds_write): thread covers (row j*64+arow, chunk achk)
  const int arow = tid >> 3;                     // 0..63
  const int achk = tid & 7;
  const int aslt = achk ^ (arow & 7);            // swizzled chunk slot
  const float* gAbase = X + (size_t)(n0 + arow) * DIM * CIN + (achk << 3);
  uint16_t* lAbase = &As[arow * 64 + aslt * 8];

  // compute geometry: wave grid 4 (rows) x 2 (cols), 64x64 per wave
  const int lr   = l & 15;
  const int quad = l >> 4;
  const int wr   = (w & 3) << 6;                 // 0,64,128,192
  const int wc   = (w >> 2) << 6;                // 0,64

  v4f acc[4][4];
  #pragma unroll
  for (int i = 0; i < 4; ++i)
    #pragma unroll
    for (int j = 0; j < 4; ++j)
      acc[i][j] = v4f{0.f, 0.f, 0.f, 0.f};

  const int nIter = nE << 1;

  // ---- prologue: stage K-step 0 (A via regs, B into Bs[0]) ----
  {
    const int irow = TAB.e_in[e0];
    const int trow = TAB.e_t[e0];
    const uint16_t* gB = Bt + ((size_t)trow * COUT + srow) * CIN + ssrc;
    load_lds16(gB,                    &Bs[0][srow * 64 + slt * 8]);
    load_lds16(gB + (size_t)64 * CIN, &Bs[0][(64 + srow) * 64 + slt * 8]);

    float4 a_st[8];
    const float* gA = gAbase + (size_t)irow * CIN;
    #pragma unroll
    for (int j = 0; j < 4; ++j) {
      const float4* p = (const float4*)(gA + (size_t)(j << 6) * (DIM * CIN));
      a_st[2 * j]     = p[0];
      a_st[2 * j + 1] = p[1];
    }
    #pragma unroll
    for (int j = 0; j < 4; ++j)
      *(v8bf*)(lAbase + (j << 6) * 64) = cvt8(a_st[2 * j], a_st[2 * j + 1]);
  }
  __syncthreads();                         // A(0), B(0) visible

  for (int ki = 0; ki < nIter; ++ki) {
    const int cur  = ki & 1;
    const bool more = (ki + 1 < nIter);

    // issue next K-step's loads BEFORE compute (latency hides under MFMAs)
    float4 a_st[8];
    if (more) {
      const int kn   = ki + 1;
      const int e    = e0 + (kn >> 1);
      const int kk   = (kn & 1) << 6;
      const int irow = TAB.e_in[e];
      const int trow = TAB.e_t[e];
      const uint16_t* gB = Bt + ((size_t)trow * COUT + srow) * CIN + kk + ssrc;
      load_lds16(gB,                    &Bs[cur ^ 1][srow * 64 + slt * 8]);
      load_lds16(gB + (size_t)64 * CIN, &Bs[cur ^ 1][(64 + srow) * 64 + slt * 8]);
      const float* gA = gAbase + (size_t)irow * CIN + kk;
      #pragma unroll
      for (int j = 0; j < 4; ++j) {
        const float4* p = (const float4*)(gA + (size_t)(j << 6) * (DIM * CIN));
        a_st[2 * j]     = p[0];
        a_st[2 * j + 1] = p[1];
      }
    }

    // compute current K-step
    #pragma unroll
    for (int kk2 = 0; kk2 < 2; ++kk2) {
      const int s = (((kk2 << 2) + quad) ^ (lr & 7)) << 3;
      v8bf a[4], b[4];
      #pragma unroll
      for (int i = 0; i < 4; ++i) {
        a[i] = *(const v8bf*)(&As[(wr + (i << 4) + lr) * 64 + s]);
        b[i] = *(const v8bf*)(&Bs[cur][(wc + (i << 4) + lr) * 64 + s]);
      }
      #pragma unroll
      for (int i = 0; i < 4; ++i)
        #pragma unroll
        for (int j = 0; j < 4; ++j)
          acc[i][j] = __builtin_amdgcn_mfma_f32_16x16x32_bf16(a[i], b[j],
                                                              acc[i][j], 0, 0, 0);
    }

    if (more) {
      __syncthreads();   // all reads of As/Bs[cur] done; vmcnt drained (A regs
                         // ready, B(k+1) landed) — drain issued a phase ago
      #pragma unroll
      for (int j = 0; j < 4; ++j)
        *(v8bf*)(lAbase + (j << 6) * 64) = cvt8(a_st[2 * j], a_st[2 * j + 1]);
      __syncthreads();   // lgkm-only drain: As(k+1) visible
    }
  }

  // epilogue: C/D layout col = lane&15 (d), row = quad*4 + r (n)
  #pragma unroll
  for (int i = 0; i < 4; ++i) {
    #pragma unroll
    for (int r = 0; r < 4; ++r) {
      const int n = n0 + wr + (i << 4) + (quad << 2) + r;
      float* op = Out + ((size_t)n * DIM + o) * COUT + wc + lr;
      #pragma unroll
      for (int j = 0; j < 4; ++j)
        op[j << 4] = acc[i][j][r];
    }
  }
}

// ---------------- launcher ---------------------------------------------------
extern "C" void kernel_launch(void* const* d_in, const int* in_sizes, int n_in,
                              void* d_out, int out_size, void* d_ws, size_t ws_size,
                              hipStream_t stream) {
  const float* X = (const float*)d_in[0];   // [8192][25][128]
  const float* W = (const float*)d_in[1];   // [85][128][128]
  float* Out = (float*)d_out;

  uint16_t* Bt = (uint16_t*)d_ws;           // 4.75 MB (only workspace use now)

  // 1) tiny weight transpose/scale (fp32 -> bf16)
  prep_kernel<<<NWB, 256, 0, stream>>>(W, Bt);
  // 2) fused cast+GEMM, XCD-swizzled 1-D grid, 256-row tiles
  so2_gemm<<<DIM * (NROWS / 256), 512, 0, stream>>>(X, Bt, Out);
}